// Round 13
// baseline (341.416 us; speedup 1.0000x reference)
//
#include <hip/hip_runtime.h>
#include <hip/hip_bf16.h>
#include <math.h>

#define NEG_SLOPE 0.2f
#define GAT_EPS 1e-16f

constexpr int NN = 50000;   // nodes
constexpr int NE = 800000;  // raw edges
constexpr int EP = NE + NN; // edges incl. self loops = 850000
constexpr int NB = (NN + 255) / 256; // scan blocks = 196
constexpr int SLICE = 6250;          // NN/8: dst-slice per XCD group
constexpr int HG = 416;              // blocks per group
constexpr int HSTRIDE = HG * 256;
constexpr int OCHUNK = (EP + 7) / 8; // out0 chunk per group

// inline decode of edge i (self loops appended past NE)
__device__ inline void edge_sd(const int* __restrict__ ei, int i, int& s, int& d) {
    if (i < NE) { s = ei[i]; d = ei[NE + i]; }
    else        { s = d = i - NE; }
}

// bf16 pair unpack (uint = 2 bf16)
__device__ inline float bflo(unsigned int h) { return __uint_as_float(h << 16); }
__device__ inline float bfhi(unsigned int h) { return __uint_as_float(h & 0xffff0000u); }

// XCD-sliced histogram + out0. Group g = blockIdx&7 (XCD heuristic) counts only
// d in its slice -> its 12.5KB counter region stays in one XCD's L2 (no bounce).
// Counters u16-packed (R12). out0 written per-group coalesced chunks (NT ok).
__global__ void k_hist_x(const int* __restrict__ ei, float* __restrict__ out0,
                         unsigned int* __restrict__ cntp) {
    int g = blockIdx.x & 7;
    int bi = blockIdx.x >> 3;
    for (int i = bi * 256 + threadIdx.x; i < EP; i += HSTRIDE) {
        int d = (i < NE) ? ei[NE + i] : i - NE;
        if (i / OCHUNK == g) {
            int s = (i < NE) ? ei[i] : i - NE;
            __builtin_nontemporal_store((float)s, &out0[i]);
            __builtin_nontemporal_store((float)d, &out0[EP + i]);
        }
        if ((unsigned)d / (unsigned)SLICE == (unsigned)g) {
            unsigned int add = (d & 1) ? 0x10000u : 1u;
            atomicAdd(&cntp[d >> 1], add);
        }
    }
}

// block-level exclusive scan of u16-packed counts; bsum[b] = block total
__global__ void k_scan1(const unsigned int* __restrict__ cntp, int* __restrict__ rowptr,
                        int* __restrict__ bsum) {
    __shared__ int sh[256];
    int t = threadIdx.x, i = blockIdx.x * 256 + t;
    int v = 0;
    if (i < NN) {
        unsigned int pv = cntp[i >> 1];
        v = (i & 1) ? (int)(pv >> 16) : (int)(pv & 0xffffu);
    }
    sh[t] = v; __syncthreads();
    for (int off = 1; off < 256; off <<= 1) {
        int x = (t >= off) ? sh[t - off] : 0;
        __syncthreads();
        sh[t] += x;
        __syncthreads();
    }
    if (i < NN) rowptr[i] = sh[t] - v;
    if (t == 255) bsum[blockIdx.x] = sh[255];
}

__global__ void k_scan2(int* __restrict__ bsum, int* __restrict__ boff) {
    __shared__ int sh[256];
    int t = threadIdx.x;
    int v = (t < NB) ? bsum[t] : 0;
    sh[t] = v; __syncthreads();
    for (int off = 1; off < 256; off <<= 1) {
        int x = (t >= off) ? sh[t - off] : 0;
        __syncthreads();
        sh[t] += x;
        __syncthreads();
    }
    if (t < NB) boff[t] = sh[t] - v;
}

// finalize rowptr and seed write cursors
__global__ void k_scan3(int* __restrict__ rowptr, const int* __restrict__ boff,
                        int* __restrict__ cur) {
    int i = blockIdx.x * blockDim.x + threadIdx.x;
    if (i < NN) {
        int r = rowptr[i] + boff[i >> 8];
        rowptr[i] = r;
        cur[i] = r;
    }
    if (i == 0) rowptr[NN] = EP;
}

// XCD-sliced CSR fill: cursor atomics + u16 col stores stay in one XCD's L2
// region (plain cached stores -> lines combine before writeback).
__global__ void k_fill_x(const int* __restrict__ ei, int* __restrict__ cur,
                         unsigned short* __restrict__ col) {
    int g = blockIdx.x & 7;
    int bi = blockIdx.x >> 3;
    for (int i = bi * 256 + threadIdx.x; i < EP; i += HSTRIDE) {
        int d = (i < NE) ? ei[NE + i] : i - NE;
        if ((unsigned)d / (unsigned)SLICE == (unsigned)g) {
            int s = (i < NE) ? ei[i] : i - NE;
            int pos = atomicAdd(&cur[d], 1);
            col[pos] = (unsigned short)s;
        }
    }
}

// edge-order alpha output (coalesced NT write; score arrays L2-resident)
__global__ void k_alpha_out(const int* __restrict__ ei, const float* __restrict__ as_,
                            const float* __restrict__ ad_, const float* __restrict__ inv,
                            float* __restrict__ out_alpha) {
    int i = blockIdx.x * blockDim.x + threadIdx.x;
    if (i >= EP) return;
    int s, d; edge_sd(ei, i, s, d);
    float v = as_[s] + ad_[d];
    v = v > 0.f ? v : NEG_SLOPE * v;
    __builtin_nontemporal_store(__expf(v) * inv[d], &out_alpha[i]);
}

// ---------------- dense GEMM + fused alpha scores ----------------
struct alignas(8) bh4 { __hip_bfloat16 a, b, c, d; };

__device__ inline void fma4(float4& acc, float x, const float4& w) {
    acc.x = fmaf(x, w.x, acc.x);
    acc.y = fmaf(x, w.y, acc.y);
    acc.z = fmaf(x, w.z, acc.z);
    acc.w = fmaf(x, w.w, acc.w);
}

template <int FIN, int FOUT, int NPB>
__global__ __launch_bounds__(256) void k_gemm_t(const float* __restrict__ in,
                                                const float* __restrict__ W,
                                                const float* __restrict__ avs,
                                                const float* __restrict__ avd,
                                                __hip_bfloat16* __restrict__ H,
                                                float* __restrict__ as_,
                                                float* __restrict__ ad_, int n) {
    constexpr int TF = FOUT / 4;
    constexpr int XS = FIN + 4;
    constexpr int WS = FOUT + 4;
    __shared__ float sX[NPB * XS];
    __shared__ float sWt[FIN * WS];
    int tid = threadIdx.x;
    for (int idx = tid; idx < FIN * FOUT; idx += 256) {
        int f = idx % FOUT, k = idx / FOUT;
        sWt[k * WS + f] = W[f * FIN + k];
    }
    int nb = blockIdx.x * NPB;
    for (int idx = tid; idx < NPB * (FIN / 4); idx += 256) {
        int node = idx / (FIN / 4), kq = idx % (FIN / 4);
        int g = nb + node;
        float4 v = make_float4(0.f, 0.f, 0.f, 0.f);
        if (g < n) v = *(const float4*)&in[(size_t)g * FIN + kq * 4];
        *(float4*)&sX[node * XS + kq * 4] = v;
    }
    __syncthreads();

    int fq = tid % TF, ng = tid / TF;
    int n0 = ng * 4;
    float4 acc0 = make_float4(0.f, 0.f, 0.f, 0.f);
    float4 acc1 = acc0, acc2 = acc0, acc3 = acc0;
    for (int k = 0; k < FIN; k += 4) {
        float4 w0 = *(const float4*)&sWt[(k + 0) * WS + fq * 4];
        float4 w1 = *(const float4*)&sWt[(k + 1) * WS + fq * 4];
        float4 w2 = *(const float4*)&sWt[(k + 2) * WS + fq * 4];
        float4 w3 = *(const float4*)&sWt[(k + 3) * WS + fq * 4];
        float4 x0 = *(const float4*)&sX[(n0 + 0) * XS + k];
        float4 x1 = *(const float4*)&sX[(n0 + 1) * XS + k];
        float4 x2 = *(const float4*)&sX[(n0 + 2) * XS + k];
        float4 x3 = *(const float4*)&sX[(n0 + 3) * XS + k];
        fma4(acc0, x0.x, w0); fma4(acc0, x0.y, w1); fma4(acc0, x0.z, w2); fma4(acc0, x0.w, w3);
        fma4(acc1, x1.x, w0); fma4(acc1, x1.y, w1); fma4(acc1, x1.z, w2); fma4(acc1, x1.w, w3);
        fma4(acc2, x2.x, w0); fma4(acc2, x2.y, w1); fma4(acc2, x2.z, w2); fma4(acc2, x2.w, w3);
        fma4(acc3, x3.x, w0); fma4(acc3, x3.y, w1); fma4(acc3, x3.z, w2); fma4(acc3, x3.w, w3);
    }
    float4 accs[4] = {acc0, acc1, acc2, acc3};
    float4 vs4 = *(const float4*)&avs[fq * 4];
    float4 vd4 = *(const float4*)&avd[fq * 4];
#pragma unroll
    for (int j = 0; j < 4; ++j) {
        int g = nb + n0 + j;
        float ps = accs[j].x * vs4.x + accs[j].y * vs4.y + accs[j].z * vs4.z + accs[j].w * vs4.w;
        float pd = accs[j].x * vd4.x + accs[j].y * vd4.y + accs[j].z * vd4.z + accs[j].w * vd4.w;
#pragma unroll
        for (int off = TF / 2; off; off >>= 1) {
            ps += __shfl_down(ps, off, TF);
            pd += __shfl_down(pd, off, TF);
        }
        if (g < n) {
            if (fq == 0) { as_[g] = ps; ad_[g] = pd; }
            bh4 o;
            o.a = __float2bfloat16(accs[j].x);
            o.b = __float2bfloat16(accs[j].y);
            o.c = __float2bfloat16(accs[j].z);
            o.d = __float2bfloat16(accs[j].w);
            *(bh4*)&H[(size_t)g * FOUT + fq * 4] = o;
        }
    }
}

// ---------------- fused per-node softmax + aggregate (one wave per node) ----------------
// H gathered as uint (bf16x2, 4 B/lane). No segment-max (scores O(+-8), exp safe).
template <int FOUT, bool RELU, bool WRITE_INV>
__global__ __launch_bounds__(256) void k_node_attn(
    const int* __restrict__ rowptr, const unsigned short* __restrict__ col,
    const float* __restrict__ as_, const float* __restrict__ ad_,
    const __hip_bfloat16* __restrict__ H, const float* __restrict__ bias,
    float* __restrict__ outp, float* __restrict__ inv_out) {
    int wid = (blockIdx.x * blockDim.x + threadIdx.x) >> 6; // node
    int lane = threadIdx.x & 63;
    if (wid >= NN) return;
    int start = rowptr[wid], end = rowptr[wid + 1];
    float adv = ad_[wid];
    const unsigned int* __restrict__ H2 = (const unsigned int*)H;

    float sloc = 0.f;
    float ax = 0.f, ay = 0.f;
    for (int c = start; c < end; c += 64) {
        int e = c + lane;
        float p = 0.f;
        int sc = 0;
        if (e < end) {
            sc = (int)col[e];
            float v = as_[sc] + adv;
            v = v > 0.f ? v : NEG_SLOPE * v;
            p = __expf(v);
        }
        sloc += p;
        int cnt = end - c; if (cnt > 64) cnt = 64;
        if (FOUT == 64) {
            int half = lane >> 5, fl = lane & 31;   // row = 32 uints
            int j = 0;
            for (; j + 8 <= cnt; j += 8) {          // 4 gathers in flight / lane
                int e0 = j + half, e1 = j + 2 + half, e2 = j + 4 + half, e3 = j + 6 + half;
                float p0 = __shfl(p, e0), p1 = __shfl(p, e1);
                float p2 = __shfl(p, e2), p3 = __shfl(p, e3);
                int s0 = __shfl(sc, e0), s1 = __shfl(sc, e1);
                int s2 = __shfl(sc, e2), s3 = __shfl(sc, e3);
                unsigned int h0 = H2[((size_t)s0 << 5) + fl];
                unsigned int h1 = H2[((size_t)s1 << 5) + fl];
                unsigned int h2 = H2[((size_t)s2 << 5) + fl];
                unsigned int h3 = H2[((size_t)s3 << 5) + fl];
                ax = fmaf(p0, bflo(h0), ax); ay = fmaf(p0, bfhi(h0), ay);
                ax = fmaf(p1, bflo(h1), ax); ay = fmaf(p1, bfhi(h1), ay);
                ax = fmaf(p2, bflo(h2), ax); ay = fmaf(p2, bfhi(h2), ay);
                ax = fmaf(p3, bflo(h3), ax); ay = fmaf(p3, bfhi(h3), ay);
            }
            for (; j < cnt; j += 2) {
                int e0 = j + half;                  // >= cnt lanes carry p=0 -> safe
                float p0 = __shfl(p, e0);
                int   s0 = __shfl(sc, e0);
                unsigned int h0 = H2[((size_t)s0 << 5) + fl];
                ax = fmaf(p0, bflo(h0), ax); ay = fmaf(p0, bfhi(h0), ay);
            }
        } else { // FOUT == 32: row = 16 uints, lane quarters -> 4 edges per step
            int q = lane >> 4, fl = lane & 15;
            int j = 0;
            for (; j + 16 <= cnt; j += 16) {        // 4 gathers in flight / lane
                int e0 = j + q, e1 = j + 4 + q, e2 = j + 8 + q, e3 = j + 12 + q;
                float p0 = __shfl(p, e0), p1 = __shfl(p, e1);
                float p2 = __shfl(p, e2), p3 = __shfl(p, e3);
                int s0 = __shfl(sc, e0), s1 = __shfl(sc, e1);
                int s2 = __shfl(sc, e2), s3 = __shfl(sc, e3);
                unsigned int h0 = H2[((size_t)s0 << 4) + fl];
                unsigned int h1 = H2[((size_t)s1 << 4) + fl];
                unsigned int h2 = H2[((size_t)s2 << 4) + fl];
                unsigned int h3 = H2[((size_t)s3 << 4) + fl];
                ax = fmaf(p0, bflo(h0), ax); ay = fmaf(p0, bfhi(h0), ay);
                ax = fmaf(p1, bflo(h1), ax); ay = fmaf(p1, bfhi(h1), ay);
                ax = fmaf(p2, bflo(h2), ax); ay = fmaf(p2, bfhi(h2), ay);
                ax = fmaf(p3, bflo(h3), ax); ay = fmaf(p3, bfhi(h3), ay);
            }
            for (; j < cnt; j += 4) {
                int e0 = j + q;
                float p0 = __shfl(p, e0);
                int   s0 = __shfl(sc, e0);
                unsigned int h0 = H2[((size_t)s0 << 4) + fl];
                ax = fmaf(p0, bflo(h0), ax); ay = fmaf(p0, bfhi(h0), ay);
            }
        }
    }
    for (int off = 32; off; off >>= 1) sloc += __shfl_xor(sloc, off);
    float inv = 1.f / (sloc + GAT_EPS);
    if (WRITE_INV && lane == 0) inv_out[wid] = inv;

    if (FOUT == 64) {
        ax += __shfl_xor(ax, 32);
        ay += __shfl_xor(ay, 32);
        if (lane < 32) {
            float2 bb = *(const float2*)&bias[lane * 2];
            float o0 = bb.x + ax * inv;
            float o1 = bb.y + ay * inv;
            if (RELU) { o0 = fmaxf(o0, 0.f); o1 = fmaxf(o1, 0.f); }
            *(float2*)&outp[((size_t)wid << 6) + lane * 2] = make_float2(o0, o1);
        }
    } else {
        ax += __shfl_xor(ax, 32); ay += __shfl_xor(ay, 32);
        ax += __shfl_xor(ax, 16); ay += __shfl_xor(ay, 16);
        if (lane < 16) {
            float2 bb = *(const float2*)&bias[lane * 2];
            float o0 = bb.x + ax * inv;
            float o1 = bb.y + ay * inv;
            if (RELU) { o0 = fmaxf(o0, 0.f); o1 = fmaxf(o1, 0.f); }
            *(float2*)&outp[((size_t)wid << 5) + lane * 2] = make_float2(o0, o1);
        }
    }
}

extern "C" void kernel_launch(void* const* d_in, const int* in_sizes, int n_in,
                              void* d_out, int out_size, void* d_ws, size_t ws_size,
                              hipStream_t stream) {
    const float* x  = (const float*)d_in[0];
    const int*   ei = (const int*)d_in[1];
    const float* W1 = (const float*)d_in[2];
    const float* as1 = (const float*)d_in[3];
    const float* ad1 = (const float*)d_in[4];
    const float* b1 = (const float*)d_in[5];
    const float* W2 = (const float*)d_in[6];
    const float* as2 = (const float*)d_in[7];
    const float* ad2 = (const float*)d_in[8];
    const float* b2 = (const float*)d_in[9];
    const float* W3 = (const float*)d_in[10];
    const float* as3 = (const float*)d_in[11];
    const float* ad3 = (const float*)d_in[12];
    const float* b3 = (const float*)d_in[13];

    float* out = (float*)d_out;
    float* out_edges = out;                 // [2, EP]
    float* out_alpha = out + 2 * EP;        // [EP]
    float* out_final = out + 3 * EP;        // [N, 32]

    char* w = (char*)d_ws;
    size_t o = 0;
    float* as_ = (float*)(w + o); o += (size_t)NN * 4;
    float* ad_ = (float*)(w + o); o += (size_t)NN * 4;
    float* inv = (float*)(w + o); o += (size_t)NN * 4;
    __hip_bfloat16* H = (__hip_bfloat16*)(w + o); o += (size_t)NN * 64 * 2; // 6.4MB
    int* rowptr = (int*)(w + o); o += ((size_t)(NN + 1) * 4 + 15) & ~15ull;
    unsigned int* cntp = (unsigned int*)(w + o); o += (size_t)(NN / 2) * 4; // 100KB
    int* cur    = (int*)(w + o); o += (size_t)NN * 4;                       // 200KB cursors
    unsigned short* col = (unsigned short*)(w + o); o += (size_t)EP * 2;    // 1.7MB
    int* bsum   = (int*)(w + o); o += 1024;
    int* boff   = (int*)(w + o); o += 1024;
    const size_t aggBytes = (size_t)NN * 64 * 4;
    float* agg = (ws_size >= o + aggBytes)
        ? (float*)(w + o)
        : (float*)d_in[0];  // safe: layer-1 GEMM consumes x before agg first written

    // CSR build + output chunk 0 (XCD-sliced atomics, u16 counters, no rank array)
    hipMemsetAsync(cntp, 0, (size_t)(NN / 2) * 4, stream);
    k_hist_x<<<8 * HG, 256, 0, stream>>>(ei, out_edges, cntp);
    k_scan1<<<NB, 256, 0, stream>>>(cntp, rowptr, bsum);
    k_scan2<<<1, 256, 0, stream>>>(bsum, boff);
    k_scan3<<<NB, 256, 0, stream>>>(rowptr, boff, cur);
    k_fill_x<<<8 * HG, 256, 0, stream>>>(ei, cur, col);

    const int nblk = (NN * 64 + 255) / 256;

    // layer 1: 128 -> 64, ReLU fused; stores inv[] for the alpha pass
    k_gemm_t<128, 64, 64><<<(NN + 63) / 64, 256, 0, stream>>>(x, W1, as1, ad1, H, as_, ad_, NN);
    k_node_attn<64, true, true><<<nblk, 256, 0, stream>>>(rowptr, col, as_, ad_, H, b1,
                                                          agg, inv);
    k_alpha_out<<<(EP + 255) / 256, 256, 0, stream>>>(ei, as_, ad_, inv, out_alpha);

    // layer 2: 64 -> 64, ReLU fused
    k_gemm_t<64, 64, 64><<<(NN + 63) / 64, 256, 0, stream>>>(agg, W2, as2, ad2, H, as_, ad_, NN);
    k_node_attn<64, true, false><<<nblk, 256, 0, stream>>>(rowptr, col, as_, ad_, H, b2,
                                                           agg, nullptr);

    // layer 3: 64 -> 32, straight into d_out chunk 2
    k_gemm_t<64, 32, 128><<<(NN + 127) / 128, 256, 0, stream>>>(agg, W3, as3, ad3, H, as_, ad_,
                                                                NN);
    k_node_attn<32, false, false><<<nblk, 256, 0, stream>>>(rowptr, col, as_, ad_, H, b3,
                                                            out_final, nullptr);
}

// Round 14
// 311.661 us; speedup vs baseline: 1.0955x; 1.0955x over previous
//
#include <hip/hip_runtime.h>
#include <hip/hip_bf16.h>
#include <math.h>

#define NEG_SLOPE 0.2f
#define GAT_EPS 1e-16f

constexpr int NN = 50000;   // nodes
constexpr int NE = 800000;  // raw edges
constexpr int EP = NE + NN; // edges incl. self loops = 850000
constexpr int NB = (NN + 255) / 256; // scan blocks = 196

// inline decode of edge i (self loops appended past NE)
__device__ inline void edge_sd(const int* __restrict__ ei, int i, int& s, int& d) {
    if (i < NE) { s = ei[i]; d = ei[NE + i]; }
    else        { s = d = i - NE; }
}

// bf16 pair unpack (uint = 2 bf16)
__device__ inline float bflo(unsigned int h) { return __uint_as_float(h << 16); }
__device__ inline float bfhi(unsigned int h) { return __uint_as_float(h & 0xffff0000u); }

// fused: out0 (coalesced NT) + histogram with u16-packed counters.
// atomicAdd return = this edge's rank within its dst segment.
__global__ void k_edges_hist(const int* __restrict__ ei, float* __restrict__ out0,
                             unsigned int* __restrict__ cntp,
                             unsigned short* __restrict__ rank) {
    int i = blockIdx.x * blockDim.x + threadIdx.x;
    if (i >= EP) return;
    int s, d; edge_sd(ei, i, s, d);
    __builtin_nontemporal_store((float)s, &out0[i]);
    __builtin_nontemporal_store((float)d, &out0[EP + i]);
    unsigned int add = (d & 1) ? 0x10000u : 1u;
    unsigned int old = atomicAdd(&cntp[d >> 1], add);
    unsigned short r = (unsigned short)((d & 1) ? (old >> 16) : (old & 0xffffu));
    __builtin_nontemporal_store(r, &rank[i]);
}

// block-level exclusive scan of u16-packed counts; bsum[b] = block total
__global__ void k_scan1(const unsigned int* __restrict__ cntp, int* __restrict__ rowptr,
                        int* __restrict__ bsum) {
    __shared__ int sh[256];
    int t = threadIdx.x, i = blockIdx.x * 256 + t;
    int v = 0;
    if (i < NN) {
        unsigned int pv = cntp[i >> 1];
        v = (i & 1) ? (int)(pv >> 16) : (int)(pv & 0xffffu);
    }
    sh[t] = v; __syncthreads();
    for (int off = 1; off < 256; off <<= 1) {
        int x = (t >= off) ? sh[t - off] : 0;
        __syncthreads();
        sh[t] += x;
        __syncthreads();
    }
    if (i < NN) rowptr[i] = sh[t] - v;
    if (t == 255) bsum[blockIdx.x] = sh[255];
}

__global__ void k_scan2(int* __restrict__ bsum, int* __restrict__ boff) {
    __shared__ int sh[256];
    int t = threadIdx.x;
    int v = (t < NB) ? bsum[t] : 0;
    sh[t] = v; __syncthreads();
    for (int off = 1; off < 256; off <<= 1) {
        int x = (t >= off) ? sh[t - off] : 0;
        __syncthreads();
        sh[t] += x;
        __syncthreads();
    }
    if (t < NB) boff[t] = sh[t] - v;
}

__global__ void k_scan3(int* __restrict__ rowptr, const int* __restrict__ boff) {
    int i = blockIdx.x * blockDim.x + threadIdx.x;
    if (i < NN) rowptr[i] += boff[i >> 8];
    if (i == 0) rowptr[NN] = EP;
}

// CSR fill, no atomics: pos = rowptr[d] + rank[i]. u16 col, PLAIN cached store
// (1.7MB col is L2-resident; lines combine before writeback).
__global__ void k_fill(const int* __restrict__ ei, const unsigned short* __restrict__ rank,
                       const int* __restrict__ rowptr, unsigned short* __restrict__ col) {
    int i = blockIdx.x * blockDim.x + threadIdx.x;
    if (i >= EP) return;
    int s, d; edge_sd(ei, i, s, d);
    int pos = rowptr[d] + (int)rank[i];
    col[pos] = (unsigned short)s;
}

// edge-order alpha output (coalesced NT write; score arrays L2-resident)
__global__ void k_alpha_out(const int* __restrict__ ei, const float* __restrict__ as_,
                            const float* __restrict__ ad_, const float* __restrict__ inv,
                            float* __restrict__ out_alpha) {
    int i = blockIdx.x * blockDim.x + threadIdx.x;
    if (i >= EP) return;
    int s, d; edge_sd(ei, i, s, d);
    float v = as_[s] + ad_[d];
    v = v > 0.f ? v : NEG_SLOPE * v;
    __builtin_nontemporal_store(__expf(v) * inv[d], &out_alpha[i]);
}

// ---------------- dense GEMM + fused alpha scores ----------------
struct alignas(8) bh4 { __hip_bfloat16 a, b, c, d; };

__device__ inline void fma4(float4& acc, float x, const float4& w) {
    acc.x = fmaf(x, w.x, acc.x);
    acc.y = fmaf(x, w.y, acc.y);
    acc.z = fmaf(x, w.z, acc.z);
    acc.w = fmaf(x, w.w, acc.w);
}

template <int FIN, int FOUT, int NPB>
__global__ __launch_bounds__(256) void k_gemm_t(const float* __restrict__ in,
                                                const float* __restrict__ W,
                                                const float* __restrict__ avs,
                                                const float* __restrict__ avd,
                                                __hip_bfloat16* __restrict__ H,
                                                float* __restrict__ as_,
                                                float* __restrict__ ad_, int n) {
    constexpr int TF = FOUT / 4;
    constexpr int XS = FIN + 4;
    constexpr int WS = FOUT + 4;
    __shared__ float sX[NPB * XS];
    __shared__ float sWt[FIN * WS];
    int tid = threadIdx.x;
    for (int idx = tid; idx < FIN * FOUT; idx += 256) {
        int f = idx % FOUT, k = idx / FOUT;
        sWt[k * WS + f] = W[f * FIN + k];
    }
    int nb = blockIdx.x * NPB;
    for (int idx = tid; idx < NPB * (FIN / 4); idx += 256) {
        int node = idx / (FIN / 4), kq = idx % (FIN / 4);
        int g = nb + node;
        float4 v = make_float4(0.f, 0.f, 0.f, 0.f);
        if (g < n) v = *(const float4*)&in[(size_t)g * FIN + kq * 4];
        *(float4*)&sX[node * XS + kq * 4] = v;
    }
    __syncthreads();

    int fq = tid % TF, ng = tid / TF;
    int n0 = ng * 4;
    float4 acc0 = make_float4(0.f, 0.f, 0.f, 0.f);
    float4 acc1 = acc0, acc2 = acc0, acc3 = acc0;
    for (int k = 0; k < FIN; k += 4) {
        float4 w0 = *(const float4*)&sWt[(k + 0) * WS + fq * 4];
        float4 w1 = *(const float4*)&sWt[(k + 1) * WS + fq * 4];
        float4 w2 = *(const float4*)&sWt[(k + 2) * WS + fq * 4];
        float4 w3 = *(const float4*)&sWt[(k + 3) * WS + fq * 4];
        float4 x0 = *(const float4*)&sX[(n0 + 0) * XS + k];
        float4 x1 = *(const float4*)&sX[(n0 + 1) * XS + k];
        float4 x2 = *(const float4*)&sX[(n0 + 2) * XS + k];
        float4 x3 = *(const float4*)&sX[(n0 + 3) * XS + k];
        fma4(acc0, x0.x, w0); fma4(acc0, x0.y, w1); fma4(acc0, x0.z, w2); fma4(acc0, x0.w, w3);
        fma4(acc1, x1.x, w0); fma4(acc1, x1.y, w1); fma4(acc1, x1.z, w2); fma4(acc1, x1.w, w3);
        fma4(acc2, x2.x, w0); fma4(acc2, x2.y, w1); fma4(acc2, x2.z, w2); fma4(acc2, x2.w, w3);
        fma4(acc3, x3.x, w0); fma4(acc3, x3.y, w1); fma4(acc3, x3.z, w2); fma4(acc3, x3.w, w3);
    }
    float4 accs[4] = {acc0, acc1, acc2, acc3};
    float4 vs4 = *(const float4*)&avs[fq * 4];
    float4 vd4 = *(const float4*)&avd[fq * 4];
#pragma unroll
    for (int j = 0; j < 4; ++j) {
        int g = nb + n0 + j;
        float ps = accs[j].x * vs4.x + accs[j].y * vs4.y + accs[j].z * vs4.z + accs[j].w * vs4.w;
        float pd = accs[j].x * vd4.x + accs[j].y * vd4.y + accs[j].z * vd4.z + accs[j].w * vd4.w;
#pragma unroll
        for (int off = TF / 2; off; off >>= 1) {
            ps += __shfl_down(ps, off, TF);
            pd += __shfl_down(pd, off, TF);
        }
        if (g < n) {
            if (fq == 0) { as_[g] = ps; ad_[g] = pd; }
            bh4 o;
            o.a = __float2bfloat16(accs[j].x);
            o.b = __float2bfloat16(accs[j].y);
            o.c = __float2bfloat16(accs[j].z);
            o.d = __float2bfloat16(accs[j].w);
            *(bh4*)&H[(size_t)g * FOUT + fq * 4] = o;
        }
    }
}

// ---------------- fused per-node softmax + aggregate (one wave per node) ----------------
// H gathered as uint (bf16x2, 4 B/lane). FOUT=64: lane halves -> 2 edges/step,
// deep tier keeps 8 gathers in flight. No segment-max (scores O(+-8), exp safe).
template <int FOUT, bool RELU, bool WRITE_INV>
__global__ __launch_bounds__(256) void k_node_attn(
    const int* __restrict__ rowptr, const unsigned short* __restrict__ col,
    const float* __restrict__ as_, const float* __restrict__ ad_,
    const __hip_bfloat16* __restrict__ H, const float* __restrict__ bias,
    float* __restrict__ outp, float* __restrict__ inv_out) {
    int wid = (blockIdx.x * blockDim.x + threadIdx.x) >> 6; // node
    int lane = threadIdx.x & 63;
    if (wid >= NN) return;
    int start = rowptr[wid], end = rowptr[wid + 1];
    float adv = ad_[wid];
    const unsigned int* __restrict__ H2 = (const unsigned int*)H;

    float sloc = 0.f;
    float ax = 0.f, ay = 0.f;
    for (int c = start; c < end; c += 64) {
        int e = c + lane;
        float p = 0.f;
        int sc = 0;
        if (e < end) {
            sc = (int)col[e];
            float v = as_[sc] + adv;
            v = v > 0.f ? v : NEG_SLOPE * v;
            p = __expf(v);
        }
        sloc += p;
        int cnt = end - c; if (cnt > 64) cnt = 64;
        if (FOUT == 64) {
            int half = lane >> 5, fl = lane & 31;   // row = 32 uints
            int j = 0;
            for (; j + 16 <= cnt; j += 16) {        // 8 gathers in flight / lane
                float pp[8]; int ss[8]; unsigned int hh[8];
#pragma unroll
                for (int k = 0; k < 8; ++k) {
                    int ek = j + 2 * k + half;
                    pp[k] = __shfl(p, ek);
                    ss[k] = __shfl(sc, ek);
                }
#pragma unroll
                for (int k = 0; k < 8; ++k) hh[k] = H2[((size_t)ss[k] << 5) + fl];
#pragma unroll
                for (int k = 0; k < 8; ++k) {
                    ax = fmaf(pp[k], bflo(hh[k]), ax);
                    ay = fmaf(pp[k], bfhi(hh[k]), ay);
                }
            }
            for (; j + 8 <= cnt; j += 8) {          // 4 gathers in flight / lane
                int e0 = j + half, e1 = j + 2 + half, e2 = j + 4 + half, e3 = j + 6 + half;
                float p0 = __shfl(p, e0), p1 = __shfl(p, e1);
                float p2 = __shfl(p, e2), p3 = __shfl(p, e3);
                int s0 = __shfl(sc, e0), s1 = __shfl(sc, e1);
                int s2 = __shfl(sc, e2), s3 = __shfl(sc, e3);
                unsigned int h0 = H2[((size_t)s0 << 5) + fl];
                unsigned int h1 = H2[((size_t)s1 << 5) + fl];
                unsigned int h2 = H2[((size_t)s2 << 5) + fl];
                unsigned int h3 = H2[((size_t)s3 << 5) + fl];
                ax = fmaf(p0, bflo(h0), ax); ay = fmaf(p0, bfhi(h0), ay);
                ax = fmaf(p1, bflo(h1), ax); ay = fmaf(p1, bfhi(h1), ay);
                ax = fmaf(p2, bflo(h2), ax); ay = fmaf(p2, bfhi(h2), ay);
                ax = fmaf(p3, bflo(h3), ax); ay = fmaf(p3, bfhi(h3), ay);
            }
            for (; j < cnt; j += 2) {
                int e0 = j + half;                  // >= cnt lanes carry p=0 -> safe
                float p0 = __shfl(p, e0);
                int   s0 = __shfl(sc, e0);
                unsigned int h0 = H2[((size_t)s0 << 5) + fl];
                ax = fmaf(p0, bflo(h0), ax); ay = fmaf(p0, bfhi(h0), ay);
            }
        } else { // FOUT == 32: row = 16 uints, lane quarters -> 4 edges per step
            int q = lane >> 4, fl = lane & 15;
            int j = 0;
            for (; j + 16 <= cnt; j += 16) {        // 4 gathers in flight / lane
                int e0 = j + q, e1 = j + 4 + q, e2 = j + 8 + q, e3 = j + 12 + q;
                float p0 = __shfl(p, e0), p1 = __shfl(p, e1);
                float p2 = __shfl(p, e2), p3 = __shfl(p, e3);
                int s0 = __shfl(sc, e0), s1 = __shfl(sc, e1);
                int s2 = __shfl(sc, e2), s3 = __shfl(sc, e3);
                unsigned int h0 = H2[((size_t)s0 << 4) + fl];
                unsigned int h1 = H2[((size_t)s1 << 4) + fl];
                unsigned int h2 = H2[((size_t)s2 << 4) + fl];
                unsigned int h3 = H2[((size_t)s3 << 4) + fl];
                ax = fmaf(p0, bflo(h0), ax); ay = fmaf(p0, bfhi(h0), ay);
                ax = fmaf(p1, bflo(h1), ax); ay = fmaf(p1, bfhi(h1), ay);
                ax = fmaf(p2, bflo(h2), ax); ay = fmaf(p2, bfhi(h2), ay);
                ax = fmaf(p3, bflo(h3), ax); ay = fmaf(p3, bfhi(h3), ay);
            }
            for (; j < cnt; j += 4) {
                int e0 = j + q;
                float p0 = __shfl(p, e0);
                int   s0 = __shfl(sc, e0);
                unsigned int h0 = H2[((size_t)s0 << 4) + fl];
                ax = fmaf(p0, bflo(h0), ax); ay = fmaf(p0, bfhi(h0), ay);
            }
        }
    }
    for (int off = 32; off; off >>= 1) sloc += __shfl_xor(sloc, off);
    float inv = 1.f / (sloc + GAT_EPS);
    if (WRITE_INV && lane == 0) inv_out[wid] = inv;

    if (FOUT == 64) {
        ax += __shfl_xor(ax, 32);
        ay += __shfl_xor(ay, 32);
        if (lane < 32) {
            float2 bb = *(const float2*)&bias[lane * 2];
            float o0 = bb.x + ax * inv;
            float o1 = bb.y + ay * inv;
            if (RELU) { o0 = fmaxf(o0, 0.f); o1 = fmaxf(o1, 0.f); }
            *(float2*)&outp[((size_t)wid << 6) + lane * 2] = make_float2(o0, o1);
        }
    } else {
        ax += __shfl_xor(ax, 32); ay += __shfl_xor(ay, 32);
        ax += __shfl_xor(ax, 16); ay += __shfl_xor(ay, 16);
        if (lane < 16) {
            float2 bb = *(const float2*)&bias[lane * 2];
            float o0 = bb.x + ax * inv;
            float o1 = bb.y + ay * inv;
            if (RELU) { o0 = fmaxf(o0, 0.f); o1 = fmaxf(o1, 0.f); }
            *(float2*)&outp[((size_t)wid << 5) + lane * 2] = make_float2(o0, o1);
        }
    }
}

extern "C" void kernel_launch(void* const* d_in, const int* in_sizes, int n_in,
                              void* d_out, int out_size, void* d_ws, size_t ws_size,
                              hipStream_t stream) {
    const float* x  = (const float*)d_in[0];
    const int*   ei = (const int*)d_in[1];
    const float* W1 = (const float*)d_in[2];
    const float* as1 = (const float*)d_in[3];
    const float* ad1 = (const float*)d_in[4];
    const float* b1 = (const float*)d_in[5];
    const float* W2 = (const float*)d_in[6];
    const float* as2 = (const float*)d_in[7];
    const float* ad2 = (const float*)d_in[8];
    const float* b2 = (const float*)d_in[9];
    const float* W3 = (const float*)d_in[10];
    const float* as3 = (const float*)d_in[11];
    const float* ad3 = (const float*)d_in[12];
    const float* b3 = (const float*)d_in[13];

    float* out = (float*)d_out;
    float* out_edges = out;                 // [2, EP]
    float* out_alpha = out + 2 * EP;        // [EP]
    float* out_final = out + 3 * EP;        // [N, 32]

    char* w = (char*)d_ws;
    size_t o = 0;
    float* as_ = (float*)(w + o); o += (size_t)NN * 4;
    float* ad_ = (float*)(w + o); o += (size_t)NN * 4;
    float* inv = (float*)(w + o); o += (size_t)NN * 4;
    __hip_bfloat16* H = (__hip_bfloat16*)(w + o); o += (size_t)NN * 64 * 2; // 6.4MB
    int* rowptr = (int*)(w + o); o += ((size_t)(NN + 1) * 4 + 15) & ~15ull;
    unsigned int* cntp = (unsigned int*)(w + o); o += (size_t)(NN / 2) * 4; // 100KB
    unsigned short* rank = (unsigned short*)(w + o); o += (size_t)EP * 2;   // 1.7MB
    unsigned short* col  = (unsigned short*)(w + o); o += (size_t)EP * 2;   // 1.7MB
    int* bsum   = (int*)(w + o); o += 1024;
    int* boff   = (int*)(w + o); o += 1024;
    const size_t aggBytes = (size_t)NN * 64 * 4;
    float* agg = (ws_size >= o + aggBytes)
        ? (float*)(w + o)
        : (float*)d_in[0];  // safe: layer-1 GEMM consumes x before agg first written

    // CSR build + output chunk 0
    hipMemsetAsync(cntp, 0, (size_t)(NN / 2) * 4, stream);
    k_edges_hist<<<(EP + 255) / 256, 256, 0, stream>>>(ei, out_edges, cntp, rank);
    k_scan1<<<NB, 256, 0, stream>>>(cntp, rowptr, bsum);
    k_scan2<<<1, 256, 0, stream>>>(bsum, boff);
    k_scan3<<<NB, 256, 0, stream>>>(rowptr, boff);
    k_fill<<<(EP + 255) / 256, 256, 0, stream>>>(ei, rank, rowptr, col);

    const int nblk = (NN * 64 + 255) / 256;

    // layer 1: 128 -> 64, ReLU fused; stores inv[] for the alpha pass
    k_gemm_t<128, 64, 64><<<(NN + 63) / 64, 256, 0, stream>>>(x, W1, as1, ad1, H, as_, ad_, NN);
    k_node_attn<64, true, true><<<nblk, 256, 0, stream>>>(rowptr, col, as_, ad_, H, b1,
                                                          agg, inv);
    k_alpha_out<<<(EP + 255) / 256, 256, 0, stream>>>(ei, as_, ad_, inv, out_alpha);

    // layer 2: 64 -> 64, ReLU fused
    k_gemm_t<64, 64, 64><<<(NN + 63) / 64, 256, 0, stream>>>(agg, W2, as2, ad2, H, as_, ad_, NN);
    k_node_attn<64, true, false><<<nblk, 256, 0, stream>>>(rowptr, col, as_, ad_, H, b2,
                                                           agg, nullptr);

    // layer 3: 64 -> 32, straight into d_out chunk 2
    k_gemm_t<64, 32, 128><<<(NN + 127) / 128, 256, 0, stream>>>(agg, W3, as3, ad3, H, as_, ad_,
                                                                NN);
    k_node_attn<32, false, false><<<nblk, 256, 0, stream>>>(rowptr, col, as_, ad_, H, b3,
                                                            out_final, nullptr);
}